// Round 3
// baseline (53.283 us; speedup 1.0000x reference)
//
#include <hip/hip_runtime.h>
#include <cmath>

typedef __bf16 bf16x8 __attribute__((ext_vector_type(8)));
typedef float f32x4 __attribute__((ext_vector_type(4)));

#define HEADS 16   // B*nH
#define TT 64      // T
#define FDIM 8192  // H*W*C
#define NCHUNK 64  // K-split chunks (raised 32->64 for occupancy: 1024 blocks = 4/CU)
#define CHUNKF 128 // FDIM / NCHUNK

// ---------------- Kernel 1: partial S = Q K^T over one f-chunk (bf16 MFMA) --------------
// grid (NCHUNK, HEADS), block 256 (4 waves, 2x2 wave tiling: each wave 32p x 32q).
// A-frag (16x32): lane l holds A[l&15][(l>>4)*8 + i]; B-frag same addressing on K rows.
// D: row=(l>>4)*4+i, col=l&15   [verified: R0/R1 passed]
__global__ __launch_bounds__(256) void qk_partial(const float* __restrict__ Q,
                                                  const float* __restrict__ Km,
                                                  float* __restrict__ part) {
    const int chunk = blockIdx.x;
    const int h     = blockIdx.y;
    const int lane  = threadIdx.x & 63;
    const int w     = threadIdx.x >> 6;
    const int pr    = (w & 1) << 5;
    const int qr    = (w >> 1) << 5;
    const int r16   = lane & 15;
    const int g     = lane >> 4;
    const int kb    = chunk * CHUNKF + (g << 3);

    const float4* qp = (const float4*)(Q  + ((size_t)h * TT + pr + r16) * FDIM + kb);
    const float4* kp = (const float4*)(Km + ((size_t)h * TT + qr + r16) * FDIM + kb);
    // row stride: FDIM/4 = 2048 float4; +16 rows = 32768 float4

    f32x4 acc[2][2] = {{{0.f,0.f,0.f,0.f},{0.f,0.f,0.f,0.f}},
                       {{0.f,0.f,0.f,0.f},{0.f,0.f,0.f,0.f}}};

    #pragma unroll
    for (int ks = 0; ks < 4; ++ks) {            // 4 k-steps of 32 f = 128 f per chunk
        bf16x8 a[2], b[2];
        #pragma unroll
        for (int t = 0; t < 2; ++t) {
            const float4 x0 = qp[(size_t)t * 32768 + ks * 8];
            const float4 x1 = qp[(size_t)t * 32768 + ks * 8 + 1];
            a[t][0]=(__bf16)x0.x; a[t][1]=(__bf16)x0.y; a[t][2]=(__bf16)x0.z; a[t][3]=(__bf16)x0.w;
            a[t][4]=(__bf16)x1.x; a[t][5]=(__bf16)x1.y; a[t][6]=(__bf16)x1.z; a[t][7]=(__bf16)x1.w;
            const float4 y0 = kp[(size_t)t * 32768 + ks * 8];
            const float4 y1 = kp[(size_t)t * 32768 + ks * 8 + 1];
            b[t][0]=(__bf16)y0.x; b[t][1]=(__bf16)y0.y; b[t][2]=(__bf16)y0.z; b[t][3]=(__bf16)y0.w;
            b[t][4]=(__bf16)y1.x; b[t][5]=(__bf16)y1.y; b[t][6]=(__bf16)y1.z; b[t][7]=(__bf16)y1.w;
        }
        #pragma unroll
        for (int i = 0; i < 2; ++i)
            #pragma unroll
            for (int j = 0; j < 2; ++j)
                acc[i][j] = __builtin_amdgcn_mfma_f32_16x16x32_bf16(a[i], b[j], acc[i][j], 0, 0, 0);
    }

    // part[chunk][h][p][q]
    float* pp = part + ((size_t)chunk * HEADS + h) * (TT * TT);
    #pragma unroll
    for (int i = 0; i < 2; ++i)
        #pragma unroll
        for (int j = 0; j < 2; ++j)
            #pragma unroll
            for (int r = 0; r < 4; ++r)
                pp[(pr + (i << 4) + (g << 2) + r) * TT + (qr + (j << 4) + r16)] = acc[i][j][r];
}

// ---------------- Kernel 2: reduce partials over chunks, scale, emit bf16 S[h][p][q] -----
__global__ __launch_bounds__(256) void reduce_sb(const float* __restrict__ part,
                                                 __bf16* __restrict__ Sbf) {
    const int e = blockIdx.x * 256 + threadIdx.x;   // 65536 elements = h*4096 + p*64 + q
    float s = 0.f;
    #pragma unroll
    for (int c = 0; c < NCHUNK; ++c)
        s += part[(size_t)c * (HEADS * TT * TT) + e];
    Sbf[e] = (__bf16)(s * (1.0f / 1024.0f));
}

// ---------------- Kernel 3: O[h][p][j] = gauss[j>>3] * sum_q S[h][p][q] * V[h][q][j] -----
// MFMA version. grid (64, HEADS), block 256 = 4 waves; wave owns 32 cols x all 64 p.
// A = S (bf16, from L2-resident 128KB buffer), B = V columns, D layout as verified.
__global__ __launch_bounds__(256) void sv_mfma(const float* __restrict__ V,
                                               const __bf16* __restrict__ Sbf,
                                               float* __restrict__ out,
                                               const float g_norm) {
    const int h    = blockIdx.y;
    const int lane = threadIdx.x & 63;
    const int w    = threadIdx.x >> 6;
    const int r16  = lane & 15;
    const int g    = lane >> 4;
    const int colbase = blockIdx.x * 128 + w * 32;

    // A-fragments: a[pt][ks] = S[pt*16 + r16][ks*32 + g*8 .. +8]  (16B loads, L2 hits)
    const __bf16* Sh = Sbf + h * (TT * TT);
    bf16x8 a[4][2];
    #pragma unroll
    for (int pt = 0; pt < 4; ++pt)
        #pragma unroll
        for (int ks = 0; ks < 2; ++ks)
            a[pt][ks] = *(const bf16x8*)(Sh + (pt * 16 + r16) * TT + ks * 32 + g * 8);

    const float* Vh = V + (size_t)h * TT * FDIM;
    f32x4 acc[4][2] = {};

    #pragma unroll
    for (int jt = 0; jt < 2; ++jt) {
        #pragma unroll
        for (int ks = 0; ks < 2; ++ks) {
            // B-fragment: lane l holds V[ks*32 + g*8 + i][colbase + jt*16 + r16]
            float vf[8];
            #pragma unroll
            for (int i = 0; i < 8; ++i)
                vf[i] = Vh[(size_t)(ks * 32 + g * 8 + i) * FDIM + colbase + jt * 16 + r16];
            bf16x8 b;
            #pragma unroll
            for (int i = 0; i < 8; ++i) b[i] = (__bf16)vf[i];
            #pragma unroll
            for (int pt = 0; pt < 4; ++pt)
                acc[pt][jt] = __builtin_amdgcn_mfma_f32_16x16x32_bf16(a[pt][ks], b, acc[pt][jt], 0, 0, 0);
        }
    }

    // Epilogue: gaussian column weight, store. col per (jt): 16-lane contiguous 64B segments.
    #pragma unroll
    for (int jt = 0; jt < 2; ++jt) {
        const int col = colbase + jt * 16 + r16;
        const int m   = col >> 3;
        const float dx = (float)(m >> 5) - 15.5f;
        const float dy = (float)(m & 31) - 15.5f;
        const float gg = expf(-(dx * dx + dy * dy) * 0.02f) * g_norm;
        #pragma unroll
        for (int pt = 0; pt < 4; ++pt)
            #pragma unroll
            for (int r = 0; r < 4; ++r) {
                const int p = pt * 16 + (g << 2) + r;
                out[(size_t)h * TT * FDIM + (size_t)p * FDIM + col] = acc[pt][jt][r] * gg;
            }
    }
}

extern "C" void kernel_launch(void* const* d_in, const int* in_sizes, int n_in,
                              void* d_out, int out_size, void* d_ws, size_t ws_size,
                              hipStream_t stream) {
    const float* Q  = (const float*)d_in[0];
    const float* Km = (const float*)d_in[1];
    const float* V  = (const float*)d_in[2];
    float* out  = (float*)d_out;
    float* part = (float*)d_out;     // 16.8 MB partials inside the 33.5 MB output buffer
    __bf16* Sbf = (__bf16*)d_ws;     // 128 KB bf16 S

    // Host-side separable Gaussian normalizer (exact, deterministic):
    double sx = 0.0;
    for (int x = 0; x < 32; ++x) { const double d = (double)x - 15.5; sx += exp(-d * d / 50.0); }
    const float g_norm = (float)(1.0 / (sx * sx));

    qk_partial<<<dim3(NCHUNK, HEADS), 256, 0, stream>>>(Q, Km, part);
    reduce_sb<<<dim3((HEADS * TT * TT) / 256), 256, 0, stream>>>(part, Sbf);
    sv_mfma<<<dim3(FDIM / 128, HEADS), 256, 0, stream>>>(V, Sbf, out, g_norm);
}

// Round 4
// 37.984 us; speedup vs baseline: 1.4028x; 1.4028x over previous
//
#include <hip/hip_runtime.h>
#include <cmath>

typedef __bf16 bf16x8 __attribute__((ext_vector_type(8)));
typedef float f32x4 __attribute__((ext_vector_type(4)));

#define HEADS 16   // B*nH
#define TT 64      // T
#define FDIM 8192  // H*W*C
#define NCHUNK 32  // K-split chunks (R2 best config)
#define CHUNKF 256 // FDIM / NCHUNK

// ---------------- Kernel 1: partial S = Q K^T over one f-chunk (bf16 MFMA) --------------
// grid (NCHUNK, HEADS), block 256 (4 waves, 2x2 wave tiling: each wave 32p x 32q).
// Verbatim R2 k1 (best round).
__global__ __launch_bounds__(256) void qk_partial(const float* __restrict__ Q,
                                                  const float* __restrict__ Km,
                                                  float* __restrict__ part) {
    const int chunk = blockIdx.x;
    const int h     = blockIdx.y;
    const int lane  = threadIdx.x & 63;
    const int w     = threadIdx.x >> 6;
    const int pr    = (w & 1) << 5;
    const int qr    = (w >> 1) << 5;
    const int r16   = lane & 15;
    const int g     = lane >> 4;
    const int kb    = chunk * CHUNKF + (g << 3);

    const float4* qp = (const float4*)(Q  + ((size_t)h * TT + pr + r16) * FDIM + kb);
    const float4* kp = (const float4*)(Km + ((size_t)h * TT + qr + r16) * FDIM + kb);

    f32x4 acc[2][2] = {{{0.f,0.f,0.f,0.f},{0.f,0.f,0.f,0.f}},
                       {{0.f,0.f,0.f,0.f},{0.f,0.f,0.f,0.f}}};

    #pragma unroll
    for (int ks = 0; ks < 8; ++ks) {            // 8 k-steps of 32 f = 256 f per chunk
        bf16x8 a[2], b[2];
        #pragma unroll
        for (int t = 0; t < 2; ++t) {
            const float4 x0 = qp[(size_t)t * 32768 + ks * 8];
            const float4 x1 = qp[(size_t)t * 32768 + ks * 8 + 1];
            a[t][0]=(__bf16)x0.x; a[t][1]=(__bf16)x0.y; a[t][2]=(__bf16)x0.z; a[t][3]=(__bf16)x0.w;
            a[t][4]=(__bf16)x1.x; a[t][5]=(__bf16)x1.y; a[t][6]=(__bf16)x1.z; a[t][7]=(__bf16)x1.w;
            const float4 y0 = kp[(size_t)t * 32768 + ks * 8];
            const float4 y1 = kp[(size_t)t * 32768 + ks * 8 + 1];
            b[t][0]=(__bf16)y0.x; b[t][1]=(__bf16)y0.y; b[t][2]=(__bf16)y0.z; b[t][3]=(__bf16)y0.w;
            b[t][4]=(__bf16)y1.x; b[t][5]=(__bf16)y1.y; b[t][6]=(__bf16)y1.z; b[t][7]=(__bf16)y1.w;
        }
        #pragma unroll
        for (int i = 0; i < 2; ++i)
            #pragma unroll
            for (int j = 0; j < 2; ++j)
                acc[i][j] = __builtin_amdgcn_mfma_f32_16x16x32_bf16(a[i], b[j], acc[i][j], 0, 0, 0);
    }

    // part[chunk][h][p][q]
    float* pp = part + ((size_t)chunk * HEADS + h) * (TT * TT);
    #pragma unroll
    for (int i = 0; i < 2; ++i)
        #pragma unroll
        for (int j = 0; j < 2; ++j)
            #pragma unroll
            for (int r = 0; r < 4; ++r)
                pp[(pr + (i << 4) + (g << 2) + r) * TT + (qr + (j << 4) + r16)] = acc[i][j][r];
}

// ---------------- Kernel 2: reduce partials over chunks, scale, emit bf16 S[h][p][q] -----
__global__ __launch_bounds__(256) void reduce_sb(const float* __restrict__ part,
                                                 __bf16* __restrict__ Sbf) {
    const int e = blockIdx.x * 256 + threadIdx.x;   // 65536 elements = h*4096 + p*64 + q
    float s = 0.f;
    #pragma unroll
    for (int c = 0; c < NCHUNK; ++c)
        s += part[(size_t)c * (HEADS * TT * TT) + e];
    Sbf[e] = (__bf16)(s * (1.0f / 1024.0f));
}

// ---------------- Kernel 3: O[h][p][j] = gauss[j>>3] * sum_q S[h][p][q] * V[h][q][j] -----
// MFMA version (verbatim R3). 72 VMEM instrs/wave -> BW-bound.
__global__ __launch_bounds__(256) void sv_mfma(const float* __restrict__ V,
                                               const __bf16* __restrict__ Sbf,
                                               float* __restrict__ out,
                                               const float g_norm) {
    const int h    = blockIdx.y;
    const int lane = threadIdx.x & 63;
    const int w    = threadIdx.x >> 6;
    const int r16  = lane & 15;
    const int g    = lane >> 4;
    const int colbase = blockIdx.x * 128 + w * 32;

    // A-fragments: a[pt][ks] = S[pt*16 + r16][ks*32 + g*8 .. +8]  (16B loads, L2 hits)
    const __bf16* Sh = Sbf + h * (TT * TT);
    bf16x8 a[4][2];
    #pragma unroll
    for (int pt = 0; pt < 4; ++pt)
        #pragma unroll
        for (int ks = 0; ks < 2; ++ks)
            a[pt][ks] = *(const bf16x8*)(Sh + (pt * 16 + r16) * TT + ks * 32 + g * 8);

    const float* Vh = V + (size_t)h * TT * FDIM;
    f32x4 acc[4][2] = {};

    #pragma unroll
    for (int jt = 0; jt < 2; ++jt) {
        #pragma unroll
        for (int ks = 0; ks < 2; ++ks) {
            // B-fragment: lane l holds V[ks*32 + g*8 + i][colbase + jt*16 + r16]
            float vf[8];
            #pragma unroll
            for (int i = 0; i < 8; ++i)
                vf[i] = Vh[(size_t)(ks * 32 + g * 8 + i) * FDIM + colbase + jt * 16 + r16];
            bf16x8 b;
            #pragma unroll
            for (int i = 0; i < 8; ++i) b[i] = (__bf16)vf[i];
            #pragma unroll
            for (int pt = 0; pt < 4; ++pt)
                acc[pt][jt] = __builtin_amdgcn_mfma_f32_16x16x32_bf16(a[pt][ks], b, acc[pt][jt], 0, 0, 0);
        }
    }

    // Epilogue: gaussian column weight, store.
    #pragma unroll
    for (int jt = 0; jt < 2; ++jt) {
        const int col = colbase + jt * 16 + r16;
        const int m   = col >> 3;
        const float dx = (float)(m >> 5) - 15.5f;
        const float dy = (float)(m & 31) - 15.5f;
        const float gg = expf(-(dx * dx + dy * dy) * 0.02f) * g_norm;
        #pragma unroll
        for (int pt = 0; pt < 4; ++pt)
            #pragma unroll
            for (int r = 0; r < 4; ++r) {
                const int p = pt * 16 + (g << 2) + r;
                out[(size_t)h * TT * FDIM + (size_t)p * FDIM + col] = acc[pt][jt][r] * gg;
            }
    }
}

extern "C" void kernel_launch(void* const* d_in, const int* in_sizes, int n_in,
                              void* d_out, int out_size, void* d_ws, size_t ws_size,
                              hipStream_t stream) {
    const float* Q  = (const float*)d_in[0];
    const float* Km = (const float*)d_in[1];
    const float* V  = (const float*)d_in[2];
    float* out  = (float*)d_out;
    float* part = (float*)d_out;     // 8.4 MB partials inside the 33.5 MB output buffer
    __bf16* Sbf = (__bf16*)d_ws;     // 128 KB bf16 S

    // Host-side separable Gaussian normalizer (exact, deterministic):
    double sx = 0.0;
    for (int x = 0; x < 32; ++x) { const double d = (double)x - 15.5; sx += exp(-d * d / 50.0); }
    const float g_norm = (float)(1.0 / (sx * sx));

    qk_partial<<<dim3(NCHUNK, HEADS), 256, 0, stream>>>(Q, Km, part);
    reduce_sb<<<dim3((HEADS * TT * TT) / 256), 256, 0, stream>>>(part, Sbf);
    sv_mfma<<<dim3(FDIM / 128, HEADS), 256, 0, stream>>>(V, Sbf, out, g_norm);
}